// Round 4
// baseline (433.486 us; speedup 1.0000x reference)
//
#include <hip/hip_runtime.h>

// ---------------------------------------------------------------------------
// FactorizedSynthesizerRandom: B=8, S=2048, D=1024, K=8
//   q = x@Wq+bq, k = x@Wk+bk  (rank-8)
//   attn = softmax(q k^T)                        -> output[1] (f32, 8x2048x2048)
//   out  = attn @ (x@Wv+bv)                      -> output[0] (f32, 8x2048x1024)
// Round 4: fuse softmax+PV. mt_kernel computes row max m and 1/T; fused_pv
// recomputes P per j-tile (cheap VALU), writes attnF once, feeds P bf16 via
// swizzled LDS straight into MFMA against V staged from XCD-local L2.
// attnB round-trip (134 MB) eliminated.
// ---------------------------------------------------------------------------

typedef __attribute__((ext_vector_type(8))) __bf16 bf16x8;
typedef __attribute__((ext_vector_type(4))) __bf16 bf16x4;
typedef __attribute__((ext_vector_type(4))) float  f32x4;
typedef unsigned int u32;

#define GLB_CAST(p) ((const __attribute__((address_space(1))) u32*)(p))
#define LDS_CAST(p) ((__attribute__((address_space(3))) u32*)(p))

#define S_BARRIER() { __builtin_amdgcn_s_barrier(); __builtin_amdgcn_sched_barrier(0); }
#define LGKM0()     { asm volatile("s_waitcnt lgkmcnt(0)" ::: "memory"); __builtin_amdgcn_sched_barrier(0); }
#define VMCNT8()    { asm volatile("s_waitcnt vmcnt(8)" ::: "memory"); __builtin_amdgcn_sched_barrier(0); }
#define VMCNT4()    { asm volatile("s_waitcnt vmcnt(4)" ::: "memory"); __builtin_amdgcn_sched_barrier(0); }
#define VMCNT0()    { asm volatile("s_waitcnt vmcnt(0)" ::: "memory"); __builtin_amdgcn_sched_barrier(0); }

static constexpr int    Bn   = 8;
static constexpr int    S    = 2048;
static constexpr int    Dd   = 1024;
static constexpr int    Mtot = Bn * S;            // 16384
static constexpr size_t OUT0 = (size_t)Bn * S * Dd;   // out elements

// workspace layout (bytes)
static constexpr size_t OFF_XBF  = 0;                          // [16384][1024] bf16
static constexpr size_t OFF_WVT  = OFF_XBF  + (size_t)Mtot * Dd * 2;   // [1024][1024] bf16 (Wv^T)
static constexpr size_t OFF_WQKT = OFF_WVT  + (size_t)Dd * Dd * 2;     // [16][1024] bf16
static constexpr size_t OFF_Q    = OFF_WQKT + (size_t)16 * Dd * 2;     // [16384][8] f32
static constexpr size_t OFF_K    = OFF_Q    + (size_t)Mtot * 8 * 4;    // [16384][8] f32
static constexpr size_t OFF_VT   = OFF_K    + (size_t)Mtot * 8 * 4;    // [8][1024][2048] bf16 (value^T)
static constexpr size_t OFF_M    = OFF_VT   + (size_t)Bn * Dd * S * 2; // [16384] f32 row max
static constexpr size_t OFF_T    = OFF_M    + (size_t)Mtot * 4;        // [16384] f32 1/rowsum
static constexpr size_t WS_NEED  = OFF_T    + (size_t)Mtot * 4;        // ~70 MB

// ---------------------------------------------------------------------------
// prep: blocks [0,4096): x f32 -> bf16 ; [4096,4352): Wv -> Wv^T bf16 ;
//       [4352,4368): [Wq|Wk]^T bf16  ([16][1024])
// ---------------------------------------------------------------------------
__global__ __launch_bounds__(256) void prep_kernel(
    const float* __restrict__ x, const float* __restrict__ Wq,
    const float* __restrict__ Wk, const float* __restrict__ Wv,
    __bf16* __restrict__ xbf, __bf16* __restrict__ wvt, __bf16* __restrict__ wqkT)
{
    __shared__ float lt[64][65];
    int bid = blockIdx.x, t = threadIdx.x;
    if (bid < 4096) {
        #pragma unroll
        for (int i = 0; i < 4; ++i) {
            size_t idx4 = (size_t)i * 1048576 + (size_t)bid * 256 + t;  // float4 index
            f32x4 v = ((const f32x4*)x)[idx4];
            bf16x4 o;
            #pragma unroll
            for (int c = 0; c < 4; ++c) o[c] = (__bf16)v[c];
            ((bf16x4*)xbf)[idx4] = o;
        }
    } else if (bid < 4352) {
        int tile = bid - 4096;             // 256 tiles of 64x64
        int tr = tile >> 4, tc = tile & 15;
        int r0 = t >> 6, c = t & 63;
        #pragma unroll
        for (int i = 0; i < 16; ++i) {
            int row = i * 4 + r0;
            lt[row][c] = Wv[(size_t)(tr * 64 + row) * 1024 + tc * 64 + c];
        }
        __syncthreads();
        #pragma unroll
        for (int i = 0; i < 16; ++i) {
            int er = i * 4 + r0;
            wvt[(size_t)(tc * 64 + er) * 1024 + tr * 64 + c] = (__bf16)lt[c][er];
        }
    } else {
        int lb = bid - 4352;               // 16 blocks cover 16*1024 elems
        #pragma unroll
        for (int i = 0; i < 4; ++i) {
            int idx = (lb * 4 + i) * 256 + t;   // 0..16383
            int n = idx >> 10, d = idx & 1023;
            float v = (n < 8) ? Wq[d * 8 + n] : Wk[d * 8 + (n & 7)];
            wqkT[n * 1024 + d] = (__bf16)v;
        }
    }
}

// ---------------------------------------------------------------------------
// q/k projection (rank-8, tiny): one wave per 16 rows, single 16x16 fragment.
// ---------------------------------------------------------------------------
__global__ __launch_bounds__(256) void qk_proj_kernel(
    const __bf16* __restrict__ xbf, const __bf16* __restrict__ wqkT,
    const float* __restrict__ bq, const float* __restrict__ bk,
    float* __restrict__ qb, float* __restrict__ kb)
{
    int t = threadIdx.x, l = t & 63, w = t >> 6;
    int mbase = (blockIdx.x * 4 + w) * 16;
    f32x4 acc = {0.f, 0.f, 0.f, 0.f};
    const __bf16* ar = xbf + (size_t)(mbase + (l & 15)) * 1024 + ((l >> 4) << 3);
    const __bf16* br = wqkT + (size_t)(l & 15) * 1024 + ((l >> 4) << 3);
    #pragma unroll 8
    for (int kk = 0; kk < 1024; kk += 32) {
        bf16x8 a = *(const bf16x8*)(ar + kk);
        bf16x8 b = *(const bf16x8*)(br + kk);
        acc = __builtin_amdgcn_mfma_f32_16x16x32_bf16(a, b, acc, 0, 0, 0);
    }
    int n = l & 15;
    float bias = (n < 8) ? bq[n] : bk[n & 7];
    #pragma unroll
    for (int r = 0; r < 4; ++r) {
        int m = mbase + ((l >> 4) << 2) + r;
        float v = acc[r] + bias;
        if (n < 8) qb[m * 8 + n] = v;
        else       kb[m * 8 + (n & 7)] = v;
    }
}

// ---------------------------------------------------------------------------
// mt: per-row softmax max + 1/sum (no attn writes). Same structure as the
// round-1 softmax kernel; thread t owns cols t*8..t*8+7 with k in registers.
// ---------------------------------------------------------------------------
__global__ __launch_bounds__(256) void mt_kernel(
    const float* __restrict__ qb, const float* __restrict__ kb,
    float* __restrict__ mArr, float* __restrict__ tArr)
{
    int bid = blockIdx.x;
    int b = bid >> 6, chunk = bid & 63;       // 64 chunks x 32 rows = 2048
    int t = threadIdx.x, l = t & 63, w = t >> 6;
    float kr[8][8];
    const float* kbb = kb + ((size_t)b << 14);
    #pragma unroll
    for (int jj = 0; jj < 8; ++jj) {
        f32x4 v0 = *(const f32x4*)(kbb + (size_t)(t * 8 + jj) * 8);
        f32x4 v1 = *(const f32x4*)(kbb + (size_t)(t * 8 + jj) * 8 + 4);
        #pragma unroll
        for (int c = 0; c < 4; ++c) { kr[jj][c] = v0[c]; kr[jj][4 + c] = v1[c]; }
    }
    __shared__ float redm[4], reds[4];
    const float* qrow = qb + ((size_t)b << 14);
    for (int ii = 0; ii < 32; ++ii) {
        int i = (chunk << 5) + ii;
        f32x4 q0 = *(const f32x4*)(qrow + (size_t)i * 8);
        f32x4 q1 = *(const f32x4*)(qrow + (size_t)i * 8 + 4);
        float e[8];
        #pragma unroll
        for (int jj = 0; jj < 8; ++jj) {
            float s = q0[0] * kr[jj][0];
            s = fmaf(q0[1], kr[jj][1], s);
            s = fmaf(q0[2], kr[jj][2], s);
            s = fmaf(q0[3], kr[jj][3], s);
            s = fmaf(q1[0], kr[jj][4], s);
            s = fmaf(q1[1], kr[jj][5], s);
            s = fmaf(q1[2], kr[jj][6], s);
            s = fmaf(q1[3], kr[jj][7], s);
            e[jj] = s;
        }
        float mx = e[0];
        #pragma unroll
        for (int jj = 1; jj < 8; ++jj) mx = fmaxf(mx, e[jj]);
        #pragma unroll
        for (int d = 1; d < 64; d <<= 1) mx = fmaxf(mx, __shfl_xor(mx, d));
        if (l == 0) redm[w] = mx;
        __syncthreads();
        mx = fmaxf(fmaxf(redm[0], redm[1]), fmaxf(redm[2], redm[3]));
        float sum = 0.f;
        #pragma unroll
        for (int jj = 0; jj < 8; ++jj) sum += __expf(e[jj] - mx);
        #pragma unroll
        for (int d = 1; d < 64; d <<= 1) sum += __shfl_xor(sum, d);
        if (l == 0) reds[w] = sum;
        __syncthreads();
        float T = (reds[0] + reds[1]) + (reds[2] + reds[3]);
        if (t == 0) {
            mArr[(b << 11) + i] = mx;
            tArr[(b << 11) + i] = 1.0f / T;
        }
        __syncthreads();
    }
}

// ---------------------------------------------------------------------------
// 8-phase GEMM (unchanged, MODE 0 only): vt = (x@Wv + bv)^T as [b][e][s] bf16.
// ---------------------------------------------------------------------------
template<int LDA>
__device__ __forceinline__ void stageA(const __bf16* Ab, char* smem,
    int slot, int kk, int c, int rowin, int sl8, int wid)
{
    __builtin_amdgcn_global_load_lds(
        GLB_CAST(Ab + (size_t)(c * 64 + rowin) * LDA + kk + sl8 * 8),
        LDS_CAST(smem + slot * 65536 + c * 8192 + wid * 1024), 16, 0, 0);
}
template<int LDA>
__device__ __forceinline__ void stageB(const __bf16* Bb, char* smem,
    int slot, int kk, int c, int rowin, int sl8, int wid)
{
    __builtin_amdgcn_global_load_lds(
        GLB_CAST(Bb + (size_t)(c * 64 + rowin) * LDA + kk + sl8 * 8),
        LDS_CAST(smem + slot * 65536 + 32768 + c * 8192 + wid * 1024), 16, 0, 0);
}

__global__ __launch_bounds__(512, 2) void gemm0_kernel(
    const __bf16* __restrict__ A, const __bf16* __restrict__ Bt,
    __bf16* __restrict__ outVt, const float* __restrict__ bv)
{
    constexpr int LDA = 1024;
    constexpr int NT  = LDA / 64;
    __shared__ __align__(1024) char smem[131072];

    int bid = blockIdx.x;
    int wg = ((bid & 7) << 5) | (bid >> 3);     // bijective XCD swizzle (nwg=256)
    int t = threadIdx.x, l = t & 63;
    int wid = t >> 6;
    int wmr = wid >> 2, wnc = wid & 3;          // wave grid 2(M) x 4(N)

    int mblk = wg >> 2, nblk = wg & 3;          // 64 x 4
    const __bf16* Ab = A + (size_t)mblk * 256 * LDA;
    const __bf16* Bb = Bt + (size_t)nblk * 256 * LDA;

    int rowin = t >> 3;                         // 0..63
    int sl8 = (t & 7) ^ (rowin & 7);            // pre-swizzled global 16B-slot
    int lr = l & 15, lk = l >> 4;

    f32x4 acc[8][4] = {};

    #pragma unroll
    for (int c = 0; c < 4; ++c) {
        stageA<LDA>(Ab, smem, 0, 0, c, rowin, sl8, wid);
        stageB<LDA>(Bb, smem, 0, 0, c, rowin, sl8, wid);
    }
    #pragma unroll
    for (int c = 0; c < 4; ++c) {
        stageA<LDA>(Ab, smem, 1, 64, c, rowin, sl8, wid);
        stageB<LDA>(Bb, smem, 1, 64, c, rowin, sl8, wid);
    }
    VMCNT8();
    S_BARRIER();

    for (int tt = 0; tt < NT; ++tt) {
        int s = tt & 1;
        const __bf16* Asl = (const __bf16*)(smem + s * 65536);
        const __bf16* Bsl = (const __bf16*)(smem + s * 65536 + 32768);
        bool pf = (tt + 2 < NT);
        int kk2 = (tt + 2) * 64;

        bf16x8 aLo[2][4], aHi[2][4], bLo[2][2], bHi[2][2];

        // ---- P0: read A-lo + B-lo; MFMA Q00
        #pragma unroll
        for (int ks = 0; ks < 2; ++ks) {
            int sa = ks * 4 + lk;
            #pragma unroll
            for (int i = 0; i < 4; ++i) {
                int ra = wmr * 128 + i * 16 + lr;
                aLo[ks][i] = *(const bf16x8*)&Asl[ra * 64 + ((sa ^ (ra & 7)) << 3)];
            }
            #pragma unroll
            for (int j = 0; j < 2; ++j) {
                int rb = wnc * 64 + j * 16 + lr;
                bLo[ks][j] = *(const bf16x8*)&Bsl[rb * 64 + ((sa ^ (rb & 7)) << 3)];
            }
        }
        S_BARRIER(); LGKM0();
        __builtin_amdgcn_s_setprio(1);
        #pragma unroll
        for (int ks = 0; ks < 2; ++ks)
            #pragma unroll
            for (int i = 0; i < 4; ++i)
                #pragma unroll
                for (int j = 0; j < 2; ++j)
                    acc[i][j] = __builtin_amdgcn_mfma_f32_16x16x32_bf16(aLo[ks][i], bLo[ks][j], acc[i][j], 0, 0, 0);
        __builtin_amdgcn_s_setprio(0);
        S_BARRIER();

        // ---- P1: read B-hi; stage A0,A2(t+2); MFMA Q01
        #pragma unroll
        for (int ks = 0; ks < 2; ++ks) {
            int sa = ks * 4 + lk;
            #pragma unroll
            for (int j = 0; j < 2; ++j) {
                int rb = wnc * 64 + (j + 2) * 16 + lr;
                bHi[ks][j] = *(const bf16x8*)&Bsl[rb * 64 + ((sa ^ (rb & 7)) << 3)];
            }
        }
        if (pf) {
            stageA<LDA>(Ab, smem, s, kk2, 0, rowin, sl8, wid);
            stageA<LDA>(Ab, smem, s, kk2, 2, rowin, sl8, wid);
        }
        S_BARRIER(); LGKM0();
        __builtin_amdgcn_s_setprio(1);
        #pragma unroll
        for (int ks = 0; ks < 2; ++ks)
            #pragma unroll
            for (int i = 0; i < 4; ++i)
                #pragma unroll
                for (int j = 0; j < 2; ++j)
                    acc[i][2 + j] = __builtin_amdgcn_mfma_f32_16x16x32_bf16(aLo[ks][i], bHi[ks][j], acc[i][2 + j], 0, 0, 0);
        __builtin_amdgcn_s_setprio(0);
        S_BARRIER();

        // ---- P2: read A-hi; stage B0-3(t+2); MFMA Q11
        #pragma unroll
        for (int ks = 0; ks < 2; ++ks) {
            int sa = ks * 4 + lk;
            #pragma unroll
            for (int i = 0; i < 4; ++i) {
                int ra = wmr * 128 + (i + 4) * 16 + lr;
                aHi[ks][i] = *(const bf16x8*)&Asl[ra * 64 + ((sa ^ (ra & 7)) << 3)];
            }
        }
        if (pf) {
            #pragma unroll
            for (int c = 0; c < 4; ++c)
                stageB<LDA>(Bb, smem, s, kk2, c, rowin, sl8, wid);
        }
        S_BARRIER(); LGKM0();
        __builtin_amdgcn_s_setprio(1);
        #pragma unroll
        for (int ks = 0; ks < 2; ++ks)
            #pragma unroll
            for (int i = 0; i < 4; ++i)
                #pragma unroll
                for (int j = 0; j < 2; ++j)
                    acc[4 + i][2 + j] = __builtin_amdgcn_mfma_f32_16x16x32_bf16(aHi[ks][i], bHi[ks][j], acc[4 + i][2 + j], 0, 0, 0);
        __builtin_amdgcn_s_setprio(0);
        S_BARRIER();

        // ---- P3: stage A1,A3(t+2); MFMA Q10
        if (pf) {
            stageA<LDA>(Ab, smem, s, kk2, 1, rowin, sl8, wid);
            stageA<LDA>(Ab, smem, s, kk2, 3, rowin, sl8, wid);
        }
        S_BARRIER();
        __builtin_amdgcn_s_setprio(1);
        #pragma unroll
        for (int ks = 0; ks < 2; ++ks)
            #pragma unroll
            for (int i = 0; i < 4; ++i)
                #pragma unroll
                for (int j = 0; j < 2; ++j)
                    acc[4 + i][j] = __builtin_amdgcn_mfma_f32_16x16x32_bf16(aHi[ks][i], bLo[ks][j], acc[4 + i][j], 0, 0, 0);
        __builtin_amdgcn_s_setprio(0);

        if (tt == NT - 1) break;
        S_BARRIER();
        if (pf) { VMCNT8(); } else { VMCNT0(); }
        S_BARRIER();
    }

    #pragma unroll
    for (int j = 0; j < 4; ++j) {
        int e = (nblk << 8) + wnc * 64 + j * 16 + lr;
        float bias = bv[e];
        #pragma unroll
        for (int i = 0; i < 8; ++i) {
            int m0 = (mblk << 8) + wmr * 128 + i * 16 + (lk << 2);
            int b = m0 >> 11, s0 = m0 & 2047;
            bf16x4 o;
            #pragma unroll
            for (int r = 0; r < 4; ++r) o[r] = (__bf16)(acc[i][j][r] + bias);
            *(bf16x4*)&outVt[(((size_t)(b << 10) + e) << 11) + s0] = o;
        }
    }
}

// ---------------------------------------------------------------------------
// fused softmax+PV: block = (b = bid&7 [XCD-affine], itile = (bid>>3)>>1,
// nh = (bid>>3)&1). Rows i0..i0+127, e-cols e0..e0+511. Per 32-j tile:
// recompute P = exp(e - m)*invT (thread (pr=t>>2, jg=t&3) -> 8 j), write
// attnF (nh==0), write P bf16 to swizzled LDS; stage V tile (512x32 bf16)
// via global_load_lds with inverse-swizzled source; 8 waves x 32 MFMA.
// LDS: V 2x32KB + P 2x8KB = 80 KB. Counted vmcnt(4), raw barriers.
// ---------------------------------------------------------------------------
__device__ __forceinline__ void stageV(const __bf16* vtb, char* smem, int vs,
    int jt0, int t, int wid)
{
    #pragma unroll
    for (int u = 0; u < 4; ++u) {
        int el = u * 128 + (t >> 2);
        int sc = (t & 3) ^ ((el >> 1) & 3);
        __builtin_amdgcn_global_load_lds(
            GLB_CAST(vtb + (size_t)el * 2048 + jt0 + sc * 8),
            LDS_CAST(smem + vs * 32768 + u * 8192 + wid * 1024), 16, 0, 0);
    }
}

__device__ __forceinline__ void pcompute(int jt0, int ps, char* smem,
    const float* kbb, f32x4 q0, f32x4 q1, float m, float invT,
    float* aF, bool writeA, int pr, int jg)
{
    float p[8];
    const float* kp = kbb + (size_t)(jt0 + jg * 8) * 8;
    #pragma unroll
    for (int jj = 0; jj < 8; ++jj) {
        f32x4 k0 = *(const f32x4*)(kp + jj * 8);
        f32x4 k1 = *(const f32x4*)(kp + jj * 8 + 4);
        float s = q0[0] * k0[0];
        s = fmaf(q0[1], k0[1], s);
        s = fmaf(q0[2], k0[2], s);
        s = fmaf(q0[3], k0[3], s);
        s = fmaf(q1[0], k1[0], s);
        s = fmaf(q1[1], k1[1], s);
        s = fmaf(q1[2], k1[2], s);
        s = fmaf(q1[3], k1[3], s);
        p[jj] = __expf(s - m) * invT;
    }
    if (writeA) {
        f32x4 o0 = {p[0], p[1], p[2], p[3]};
        f32x4 o1 = {p[4], p[5], p[6], p[7]};
        *(f32x4*)(aF + jt0 + jg * 8) = o0;
        *(f32x4*)(aF + jt0 + jg * 8 + 4) = o1;
    }
    bf16x8 pb;
    #pragma unroll
    for (int c = 0; c < 8; ++c) pb[c] = (__bf16)p[c];
    int sl = jg ^ ((pr >> 1) & 3);
    *(bf16x8*)(smem + 65536 + ps * 8192 + pr * 64 + (sl << 4)) = pb;
}

__global__ __launch_bounds__(512, 2) void fused_pv_kernel(
    const float* __restrict__ qb, const float* __restrict__ kb,
    const float* __restrict__ mArr, const float* __restrict__ tArr,
    const __bf16* __restrict__ vt, float* __restrict__ attnF,
    float* __restrict__ outp)
{
    __shared__ __align__(1024) char smem[81920];
    int bid = blockIdx.x;
    int b = bid & 7, rr = bid >> 3;             // batch b -> XCD b
    int itile = rr >> 1, nh = rr & 1;
    int i0 = itile * 128, e0 = nh * 512;
    int t = threadIdx.x, l = t & 63, wid = t >> 6;
    int lr = l & 15, lk = l >> 4;

    // P-compute thread mapping
    int pr = t >> 2, jg = t & 3;
    int grow = (b << 11) + i0 + pr;             // global row index
    const float* qrow = qb + (size_t)grow * 8;
    f32x4 q0 = *(const f32x4*)(qrow);
    f32x4 q1 = *(const f32x4*)(qrow + 4);
    float m    = mArr[grow];
    float invT = tArr[grow];
    const float* kbb = kb + ((size_t)b << 14);
    const __bf16* vtb = vt + (((size_t)(b << 10) + e0) << 11);
    float* aF = attnF + ((size_t)grow << 11);
    bool writeA = (nh == 0);

    f32x4 acc[8][4] = {};

    // prologue: tile 0 P + V
    pcompute(0, 0, smem, kbb, q0, q1, m, invT, aF, writeA, pr, jg);
    stageV(vtb, smem, 0, 0, t, wid);
    VMCNT0(); LGKM0();
    S_BARRIER();

    for (int tt = 0; tt < 64; ++tt) {
        int s = tt & 1;
        if (tt < 63) {
            pcompute((tt + 1) * 32, s ^ 1, smem, kbb, q0, q1, m, invT, aF, writeA, pr, jg);
            stageV(vtb, smem, s ^ 1, (tt + 1) * 32, t, wid);
            VMCNT4();
        } else {
            VMCNT0();
        }
        LGKM0();
        S_BARRIER();

        const char* Vs = smem + s * 32768;
        const char* Ps = smem + 65536 + s * 8192;
        bf16x8 bfr[4];
        #pragma unroll
        for (int eb = 0; eb < 4; ++eb) {
            int el = wid * 64 + eb * 16 + lr;
            bfr[eb] = *(const bf16x8*)(Vs + el * 64 + ((lk ^ ((el >> 1) & 3)) << 4));
        }
        __builtin_amdgcn_s_setprio(1);
        #pragma unroll
        for (int i = 0; i < 8; ++i) {
            int row = i * 16 + lr;
            bf16x8 af = *(const bf16x8*)(Ps + row * 64 + ((lk ^ ((row >> 1) & 3)) << 4));
            #pragma unroll
            for (int eb = 0; eb < 4; ++eb)
                acc[i][eb] = __builtin_amdgcn_mfma_f32_16x16x32_bf16(af, bfr[eb], acc[i][eb], 0, 0, 0);
        }
        __builtin_amdgcn_s_setprio(0);
        S_BARRIER();
    }

    float* ob = outp + ((size_t)b << 21);
    #pragma unroll
    for (int i = 0; i < 8; ++i) {
        int m0 = i0 + i * 16 + (lk << 2);
        #pragma unroll
        for (int eb = 0; eb < 4; ++eb) {
            int e = e0 + wid * 64 + eb * 16 + lr;
            #pragma unroll
            for (int r = 0; r < 4; ++r)
                ob[(size_t)(m0 + r) * 1024 + e] = acc[i][eb][r];
        }
    }
}

// ---------------------------------------------------------------------------
extern "C" void kernel_launch(void* const* d_in, const int* in_sizes, int n_in,
                              void* d_out, int out_size, void* d_ws, size_t ws_size,
                              hipStream_t stream)
{
    const float* x  = (const float*)d_in[0];
    const float* Wq = (const float*)d_in[1];
    const float* bq = (const float*)d_in[2];
    const float* Wk = (const float*)d_in[3];
    const float* bk = (const float*)d_in[4];
    const float* Wv = (const float*)d_in[5];
    const float* bv = (const float*)d_in[6];

    float* outp  = (float*)d_out;
    float* attnF = outp + OUT0;

    if (ws_size < WS_NEED) return;
    char* ws = (char*)d_ws;
    __bf16* xbf   = (__bf16*)(ws + OFF_XBF);
    __bf16* wvt   = (__bf16*)(ws + OFF_WVT);
    __bf16* wqkT  = (__bf16*)(ws + OFF_WQKT);
    float*  qbuf  = (float*)(ws + OFF_Q);
    float*  kbuf  = (float*)(ws + OFF_K);
    __bf16* vt    = (__bf16*)(ws + OFF_VT);
    float*  mArr  = (float*)(ws + OFF_M);
    float*  tArr  = (float*)(ws + OFF_T);

    prep_kernel<<<4368, 256, 0, stream>>>(x, Wq, Wk, Wv, xbf, wvt, wqkT);
    qk_proj_kernel<<<256, 256, 0, stream>>>(xbf, wqkT, bq, bk, qbuf, kbuf);
    mt_kernel<<<512, 256, 0, stream>>>(qbuf, kbuf, mArr, tArr);
    gemm0_kernel<<<256, 512, 0, stream>>>(xbf, wvt, vt, bv);
    fused_pv_kernel<<<256, 512, 0, stream>>>(qbuf, kbuf, mArr, tArr, vt, attnF, outp);
}

// Round 5
// 200.129 us; speedup vs baseline: 2.1660x; 2.1660x over previous
//
#include <hip/hip_runtime.h>

// ---------------------------------------------------------------------------
// FactorizedSynthesizerRandom: B=8, S=2048, D=1024, K=8
//   q = x@Wq+bq, k = x@Wk+bk  (rank-8)
//   attn = softmax(q k^T)                        -> output[1] (f32, 8x2048x2048)
//   out  = attn @ (x@Wv+bv)                      -> output[0] (f32, 8x2048x1024)
// Round 5: revert round-4 fusion (latency-bound, 328us). Round-3 pipeline +
//  (a) qk folded into prep grid (reads f32 x/Wq/Wk directly; no launch),
//  (b) gemm inner loop with hoisted lane-constant LDS offsets (row-XOR key
//      (lr&7) is lane-invariant) + offset-immediate ds_reads, monolithic
//      2-barrier/tile counted-vmcnt(8) schedule (round-2 structure).
// ---------------------------------------------------------------------------

typedef __attribute__((ext_vector_type(8))) __bf16 bf16x8;
typedef __attribute__((ext_vector_type(4))) __bf16 bf16x4;
typedef __attribute__((ext_vector_type(4))) float  f32x4;
typedef unsigned int u32;

#define GLB_CAST(p) ((const __attribute__((address_space(1))) u32*)(p))
#define LDS_CAST(p) ((__attribute__((address_space(3))) u32*)(p))

#define S_BARRIER() { __builtin_amdgcn_s_barrier(); __builtin_amdgcn_sched_barrier(0); }
#define VMCNT8()    { asm volatile("s_waitcnt vmcnt(8)" ::: "memory"); __builtin_amdgcn_sched_barrier(0); }
#define VMCNT0()    { asm volatile("s_waitcnt vmcnt(0)" ::: "memory"); __builtin_amdgcn_sched_barrier(0); }

static constexpr int    Bn   = 8;
static constexpr int    S    = 2048;
static constexpr int    Dd   = 1024;
static constexpr int    Mtot = Bn * S;            // 16384
static constexpr size_t OUT0 = (size_t)Bn * S * Dd;

// workspace layout (bytes)
static constexpr size_t OFF_XBF  = 0;                                  // [16384][1024] bf16
static constexpr size_t OFF_WVT  = OFF_XBF + (size_t)Mtot * Dd * 2;    // [1024][1024] bf16 (Wv^T)
static constexpr size_t OFF_Q    = OFF_WVT + (size_t)Dd * Dd * 2;      // [16384][8] f32
static constexpr size_t OFF_K    = OFF_Q   + (size_t)Mtot * 8 * 4;     // [16384][8] f32
static constexpr size_t OFF_VT   = OFF_K   + (size_t)Mtot * 8 * 4;     // [8][1024][2048] bf16
static constexpr size_t OFF_ATTB = OFF_VT  + (size_t)Bn * Dd * S * 2;  // [8][2048][2048] bf16
static constexpr size_t WS_NEED  = OFF_ATTB + (size_t)Bn * S * S * 2;  // ~131 MB

// ---------------------------------------------------------------------------
// prep: blocks [0,256): q/k projection straight from f32 x, Wq, Wk (bf16 MFMA,
//       ordered FIRST so they overlap the BW-bound conversion blocks);
//       [256,512): Wv -> Wv^T bf16 ; [512,4608): x f32 -> bf16.
// ---------------------------------------------------------------------------
__global__ __launch_bounds__(256) void prep_kernel(
    const float* __restrict__ x, const float* __restrict__ Wq,
    const float* __restrict__ Wk, const float* __restrict__ Wv,
    const float* __restrict__ bq, const float* __restrict__ bk,
    __bf16* __restrict__ xbf, __bf16* __restrict__ wvt,
    float* __restrict__ qb, float* __restrict__ kb)
{
    __shared__ float lt[64][65];
    int bid = blockIdx.x, t = threadIdx.x;
    if (bid < 256) {
        // ---- q/k projection: 4 waves x 16 rows; one 16x16 C-fragment/wave.
        int l = t & 63, w = t >> 6;
        int mbase = (bid * 4 + w) * 16;
        int n = l & 15;
        int dbase = (l >> 4) << 3;
        const float* xr = x + (size_t)(mbase + n) * 1024 + dbase;
        const float* wcol = (n < 8) ? (Wq + n) : (Wk + (n & 7));
        f32x4 acc = {0.f, 0.f, 0.f, 0.f};
        #pragma unroll 4
        for (int kk = 0; kk < 1024; kk += 32) {
            f32x4 a0 = *(const f32x4*)(xr + kk);
            f32x4 a1 = *(const f32x4*)(xr + kk + 4);
            bf16x8 a, b;
            #pragma unroll
            for (int c = 0; c < 4; ++c) { a[c] = (__bf16)a0[c]; a[4 + c] = (__bf16)a1[c]; }
            #pragma unroll
            for (int u = 0; u < 8; ++u) b[u] = (__bf16)wcol[(size_t)(dbase + kk + u) * 8];
            acc = __builtin_amdgcn_mfma_f32_16x16x32_bf16(a, b, acc, 0, 0, 0);
        }
        float bias = (n < 8) ? bq[n] : bk[n & 7];
        #pragma unroll
        for (int r = 0; r < 4; ++r) {
            int m = mbase + ((l >> 4) << 2) + r;
            float v = acc[r] + bias;
            if (n < 8) qb[m * 8 + n] = v;
            else       kb[m * 8 + (n & 7)] = v;
        }
    } else if (bid < 512) {
        // ---- Wv transpose (bf16): 256 tiles of 64x64
        int tile = bid - 256;
        int tr = tile >> 4, tc = tile & 15;
        int r0 = t >> 6, c = t & 63;
        #pragma unroll
        for (int i = 0; i < 16; ++i) {
            int row = i * 4 + r0;
            lt[row][c] = Wv[(size_t)(tr * 64 + row) * 1024 + tc * 64 + c];
        }
        __syncthreads();
        #pragma unroll
        for (int i = 0; i < 16; ++i) {
            int er = i * 4 + r0;
            wvt[(size_t)(tc * 64 + er) * 1024 + tr * 64 + c] = (__bf16)lt[c][er];
        }
    } else {
        // ---- x f32 -> bf16
        int bid2 = bid - 512;
        #pragma unroll
        for (int i = 0; i < 4; ++i) {
            size_t idx4 = (size_t)i * 1048576 + (size_t)bid2 * 256 + t;
            f32x4 v = ((const f32x4*)x)[idx4];
            bf16x4 o;
            #pragma unroll
            for (int c = 0; c < 4; ++c) o[c] = (__bf16)v[c];
            ((bf16x4*)xbf)[idx4] = o;
        }
    }
}

// ---------------------------------------------------------------------------
// softmax: thread t owns cols j = t*8..t*8+7, k-slice in registers.
// Writes attn f32 (d_out) and attn bf16 (ws, PV GEMM input).
// ---------------------------------------------------------------------------
__global__ __launch_bounds__(256) void softmax_kernel(
    const float* __restrict__ qb, const float* __restrict__ kb,
    float* __restrict__ attnF, __bf16* __restrict__ attnB)
{
    int bid = blockIdx.x;
    int b = bid >> 6, chunk = bid & 63;       // 64 chunks x 32 rows = 2048
    int t = threadIdx.x, l = t & 63, w = t >> 6;
    float kr[8][8];
    const float* kbb = kb + ((size_t)b << 14);
    #pragma unroll
    for (int jj = 0; jj < 8; ++jj) {
        f32x4 v0 = *(const f32x4*)(kbb + (size_t)(t * 8 + jj) * 8);
        f32x4 v1 = *(const f32x4*)(kbb + (size_t)(t * 8 + jj) * 8 + 4);
        #pragma unroll
        for (int c = 0; c < 4; ++c) { kr[jj][c] = v0[c]; kr[jj][4 + c] = v1[c]; }
    }
    __shared__ float redm[4], reds[4];
    const float* qrow = qb + ((size_t)b << 14);
    for (int ii = 0; ii < 32; ++ii) {
        int i = (chunk << 5) + ii;
        f32x4 q0 = *(const f32x4*)(qrow + (size_t)i * 8);
        f32x4 q1 = *(const f32x4*)(qrow + (size_t)i * 8 + 4);
        float e[8];
        #pragma unroll
        for (int jj = 0; jj < 8; ++jj) {
            float s = q0[0] * kr[jj][0];
            s = fmaf(q0[1], kr[jj][1], s);
            s = fmaf(q0[2], kr[jj][2], s);
            s = fmaf(q0[3], kr[jj][3], s);
            s = fmaf(q1[0], kr[jj][4], s);
            s = fmaf(q1[1], kr[jj][5], s);
            s = fmaf(q1[2], kr[jj][6], s);
            s = fmaf(q1[3], kr[jj][7], s);
            e[jj] = s;
        }
        float mx = e[0];
        #pragma unroll
        for (int jj = 1; jj < 8; ++jj) mx = fmaxf(mx, e[jj]);
        #pragma unroll
        for (int d = 1; d < 64; d <<= 1) mx = fmaxf(mx, __shfl_xor(mx, d));
        if (l == 0) redm[w] = mx;
        __syncthreads();
        mx = fmaxf(fmaxf(redm[0], redm[1]), fmaxf(redm[2], redm[3]));
        float p[8], sum = 0.f;
        #pragma unroll
        for (int jj = 0; jj < 8; ++jj) { p[jj] = __expf(e[jj] - mx); sum += p[jj]; }
        #pragma unroll
        for (int d = 1; d < 64; d <<= 1) sum += __shfl_xor(sum, d);
        if (l == 0) reds[w] = sum;
        __syncthreads();
        float T = (reds[0] + reds[1]) + (reds[2] + reds[3]);
        float inv = 1.0f / T;
        size_t off = (((size_t)b << 11) + i) * 2048 + (size_t)t * 8;
        f32x4 o0, o1; bf16x8 ob;
        #pragma unroll
        for (int c = 0; c < 4; ++c) {
            o0[c] = p[c] * inv; o1[c] = p[4 + c] * inv;
            ob[c] = (__bf16)o0[c]; ob[4 + c] = (__bf16)o1[c];
        }
        *(f32x4*)(attnF + off) = o0;
        *(f32x4*)(attnF + off + 4) = o1;
        *(bf16x8*)(attnB + off) = ob;
    }
}

// ---------------------------------------------------------------------------
// GEMM: C[256x256] = A[M][Kz] * Bt[N][Kz]^T (bf16 row-major, stride Kz).
// 512 thr = 8 waves (2M x 4N), 128x64 out/wave, 2-slot 128KiB LDS, 16B-slot
// XOR swizzle (slot ^= row&7) via pre-swizzled global source. Hoisted
// lane-constant offsets: row&7 == lr&7 for all fragment rows, so reads are
// base + i*1024 (elements) -> ds_read offset immediates. Monolithic loop:
// reads+MFMA -> barrier -> stage(t+2,slot s) -> vmcnt(8) -> barrier.
// MODE 0: vt = (x@Wv+bv)^T bf16 [b][e][s]   (A=xbf, Bt=WvT, K=1024)
// MODE 1: out = attn @ value f32 [b][i][e]  (A=attnB, Bt=vt, K=2048)
// ---------------------------------------------------------------------------
template<int MODE>
__global__ __launch_bounds__(512, 2) void gemm_kernel(
    const __bf16* __restrict__ A, const __bf16* __restrict__ Bt,
    float* __restrict__ outF, __bf16* __restrict__ outVt,
    const float* __restrict__ bv)
{
    constexpr int LDA = (MODE == 0) ? 1024 : 2048;
    constexpr int NT  = LDA / 64;
    __shared__ __align__(1024) char smem[131072];

    int bid = blockIdx.x;
    int wg = ((bid & 7) << 5) | (bid >> 3);     // bijective XCD swizzle (nwg=256)
    int t = threadIdx.x, l = t & 63;
    int wid = t >> 6;
    int wmr = wid >> 2, wnc = wid & 3;          // wave grid 2(M) x 4(N)

    int mblk, nblk, bb = 0;
    size_t aoff, boff;
    if constexpr (MODE == 0) {
        mblk = wg >> 2; nblk = wg & 3;          // 64 x 4
        aoff = (size_t)mblk * 256 * LDA; boff = 0;
    } else {
        bb = wg >> 5; int r = wg & 31;          // one batch per XCD
        mblk = r >> 2; nblk = r & 3;            // 8 x 4
        aoff = (size_t)bb * S * S + (size_t)mblk * 256 * LDA;
        boff = (size_t)bb * Dd * S;
    }
    const __bf16* Ab = A + aoff;
    const __bf16* Bb = Bt + boff + (size_t)nblk * 256 * LDA;

    int rowin = t >> 3;                         // 0..63
    int sl8 = (t & 7) ^ (rowin & 7);            // pre-swizzled global 16B-slot
    int lr = l & 15, lk = l >> 4;

    // hoisted lane-constant LDS element offsets (row&7 == lr&7)
    int slot0 = (lk ^ (lr & 7)) << 3;
    int slot1 = ((lk ^ 4) ^ (lr & 7)) << 3;
    int offA0 = (wmr * 128 + lr) * 64 + slot0;
    int offA1 = (wmr * 128 + lr) * 64 + slot1;
    int offB0 = (wnc * 64 + lr) * 64 + slot0;
    int offB1 = (wnc * 64 + lr) * 64 + slot1;

    // hoisted staging source pointers (c = 64-row chunk)
    const __bf16* gA[4]; const __bf16* gB[4];
    #pragma unroll
    for (int c = 0; c < 4; ++c) {
        gA[c] = Ab + (size_t)(c * 64 + rowin) * LDA + sl8 * 8;
        gB[c] = Bb + (size_t)(c * 64 + rowin) * LDA + sl8 * 8;
    }

    f32x4 acc[8][4] = {};

    // prologue: stage tiles 0 (slot0) and 1 (slot1); wait tile0.
    #pragma unroll
    for (int c = 0; c < 4; ++c) {
        __builtin_amdgcn_global_load_lds(GLB_CAST(gA[c]),
            LDS_CAST(smem + c * 8192 + wid * 1024), 16, 0, 0);
        __builtin_amdgcn_global_load_lds(GLB_CAST(gB[c]),
            LDS_CAST(smem + 32768 + c * 8192 + wid * 1024), 16, 0, 0);
    }
    #pragma unroll
    for (int c = 0; c < 4; ++c) {
        __builtin_amdgcn_global_load_lds(GLB_CAST(gA[c] + 64),
            LDS_CAST(smem + 65536 + c * 8192 + wid * 1024), 16, 0, 0);
        __builtin_amdgcn_global_load_lds(GLB_CAST(gB[c] + 64),
            LDS_CAST(smem + 65536 + 32768 + c * 8192 + wid * 1024), 16, 0, 0);
    }
    VMCNT8();
    S_BARRIER();

    for (int tt = 0; tt < NT; ++tt) {
        const __bf16* Asl = (const __bf16*)(smem + ((tt & 1) << 16));
        const __bf16* Bsl = Asl + 16384;
        bf16x8 af[8], bfr[4];

        // ks = 0
        #pragma unroll
        for (int i = 0; i < 8; ++i) af[i] = *(const bf16x8*)(Asl + offA0 + i * 1024);
        #pragma unroll
        for (int j = 0; j < 4; ++j) bfr[j] = *(const bf16x8*)(Bsl + offB0 + j * 1024);
        __builtin_amdgcn_s_setprio(1);
        #pragma unroll
        for (int i = 0; i < 8; ++i)
            #pragma unroll
            for (int j = 0; j < 4; ++j)
                acc[i][j] = __builtin_amdgcn_mfma_f32_16x16x32_bf16(af[i], bfr[j], acc[i][j], 0, 0, 0);
        __builtin_amdgcn_s_setprio(0);

        // ks = 1
        #pragma unroll
        for (int i = 0; i < 8; ++i) af[i] = *(const bf16x8*)(Asl + offA1 + i * 1024);
        #pragma unroll
        for (int j = 0; j < 4; ++j) bfr[j] = *(const bf16x8*)(Bsl + offB1 + j * 1024);
        __builtin_amdgcn_s_setprio(1);
        #pragma unroll
        for (int i = 0; i < 8; ++i)
            #pragma unroll
            for (int j = 0; j < 4; ++j)
                acc[i][j] = __builtin_amdgcn_mfma_f32_16x16x32_bf16(af[i], bfr[j], acc[i][j], 0, 0, 0);
        __builtin_amdgcn_s_setprio(0);

        if (tt == NT - 1) break;
        S_BARRIER();                             // all waves done reading slot s
        if (tt + 2 < NT) {
            int kk2 = (tt + 2) * 64;
            char* dst = smem + ((tt & 1) << 16);
            #pragma unroll
            for (int c = 0; c < 4; ++c) {
                __builtin_amdgcn_global_load_lds(GLB_CAST(gA[c] + kk2),
                    LDS_CAST(dst + c * 8192 + wid * 1024), 16, 0, 0);
                __builtin_amdgcn_global_load_lds(GLB_CAST(gB[c] + kk2),
                    LDS_CAST(dst + 32768 + c * 8192 + wid * 1024), 16, 0, 0);
            }
            VMCNT8();                            // tile t+1 landed; t+2 in flight
        } else {
            VMCNT0();
        }
        S_BARRIER();                             // tile t+1 visible
    }

    int lr2 = l & 15, lk2 = l >> 4;
    if constexpr (MODE == 0) {
        #pragma unroll
        for (int j = 0; j < 4; ++j) {
            int e = (nblk << 8) + wnc * 64 + j * 16 + lr2;
            float bias = bv[e];
            #pragma unroll
            for (int i = 0; i < 8; ++i) {
                int m0 = (mblk << 8) + wmr * 128 + i * 16 + (lk2 << 2);
                int b = m0 >> 11, s0 = m0 & 2047;
                bf16x4 o;
                #pragma unroll
                for (int r = 0; r < 4; ++r) o[r] = (__bf16)(acc[i][j][r] + bias);
                *(bf16x4*)&outVt[(((size_t)(b << 10) + e) << 11) + s0] = o;
            }
        }
    } else {
        float* ob = outF + (size_t)bb * S * Dd;
        #pragma unroll
        for (int i = 0; i < 8; ++i) {
            int m0 = (mblk << 8) + wmr * 128 + i * 16 + (lk2 << 2);
            #pragma unroll
            for (int j = 0; j < 4; ++j) {
                int e = (nblk << 8) + wnc * 64 + j * 16 + lr2;
                #pragma unroll
                for (int r = 0; r < 4; ++r)
                    ob[(size_t)(m0 + r) * 1024 + e] = acc[i][j][r];
            }
        }
    }
}

// ---------------------------------------------------------------------------
extern "C" void kernel_launch(void* const* d_in, const int* in_sizes, int n_in,
                              void* d_out, int out_size, void* d_ws, size_t ws_size,
                              hipStream_t stream)
{
    const float* x  = (const float*)d_in[0];
    const float* Wq = (const float*)d_in[1];
    const float* bq = (const float*)d_in[2];
    const float* Wk = (const float*)d_in[3];
    const float* bk = (const float*)d_in[4];
    const float* Wv = (const float*)d_in[5];
    const float* bv = (const float*)d_in[6];

    float* outp  = (float*)d_out;
    float* attnF = outp + OUT0;

    if (ws_size < WS_NEED) return;
    char* ws = (char*)d_ws;
    __bf16* xbf   = (__bf16*)(ws + OFF_XBF);
    __bf16* wvt   = (__bf16*)(ws + OFF_WVT);
    float*  qbuf  = (float*)(ws + OFF_Q);
    float*  kbuf  = (float*)(ws + OFF_K);
    __bf16* vt    = (__bf16*)(ws + OFF_VT);
    __bf16* attnB = (__bf16*)(ws + OFF_ATTB);

    prep_kernel<<<4608, 256, 0, stream>>>(x, Wq, Wk, Wv, bq, bk, xbf, wvt, qbuf, kbuf);
    gemm_kernel<0><<<256, 512, 0, stream>>>(xbf, wvt, nullptr, vt, bv);
    softmax_kernel<<<512, 256, 0, stream>>>(qbuf, kbuf, attnF, attnB);
    gemm_kernel<1><<<256, 512, 0, stream>>>(attnB, vt, outp, nullptr, nullptr);
}